// Round 1
// baseline (3564.737 us; speedup 1.0000x reference)
//
#include <hip/hip_runtime.h>
#include <math.h>

#define NNODE 50000
#define NEDGE 800000
#define NFEAT 256
#define NHID  128
#define NTEST 5000
#define NTRAIN 5000
#define NCLS  16
#define TOPK  20

// ---------------- GEMM: C[M x 128] = op(A)[M x KT] @ B[KT x 128] ----------------
// Block: 256 thr = 16x16, BM=64, BN=128 (full), BK=32. Each thread: 4 rows x 8 cols.
template<int KT, bool RELU>
__global__ __launch_bounds__(256)
void gemm128(const float* __restrict__ A, const float* __restrict__ B,
             float* __restrict__ C, int M) {
  __shared__ float As[32][68];   // [k][m], +4 pad
  __shared__ float Bs[32][128];  // [k][n]
  const int tid = threadIdx.x;
  const int ty = tid >> 4, tx = tid & 15;
  const int m0 = blockIdx.x * 64;
  float acc[4][8];
#pragma unroll
  for (int i = 0; i < 4; ++i)
#pragma unroll
    for (int j = 0; j < 8; ++j) acc[i][j] = 0.f;

  for (int k0 = 0; k0 < KT; k0 += 32) {
    // stage A tile (64 rows x 32 k), transposed into LDS
#pragma unroll
    for (int p = 0; p < 2; ++p) {
      int li = p * 256 + tid;          // 0..511
      int r  = li >> 3;                // 0..63
      int kc = (li & 7) << 2;          // 0,4,..,28
      int gr = m0 + r; if (gr > M - 1) gr = M - 1;
      float4 v = *reinterpret_cast<const float4*>(&A[(size_t)gr * KT + k0 + kc]);
      if (RELU) { v.x=fmaxf(v.x,0.f); v.y=fmaxf(v.y,0.f); v.z=fmaxf(v.z,0.f); v.w=fmaxf(v.w,0.f); }
      As[kc+0][r]=v.x; As[kc+1][r]=v.y; As[kc+2][r]=v.z; As[kc+3][r]=v.w;
    }
    // stage B tile (32 k x 128 n)
#pragma unroll
    for (int p = 0; p < 4; ++p) {
      int li = p * 256 + tid;          // 0..1023
      int r  = li >> 5;                // 0..31
      int c4 = (li & 31) << 2;         // 0..124
      *reinterpret_cast<float4*>(&Bs[r][c4]) =
        *reinterpret_cast<const float4*>(&B[(size_t)(k0 + r) * 128 + c4]);
    }
    __syncthreads();
#pragma unroll
    for (int k = 0; k < 32; ++k) {
      float4 a  = *reinterpret_cast<const float4*>(&As[k][ty << 2]);
      float4 b0 = *reinterpret_cast<const float4*>(&Bs[k][tx << 2]);
      float4 b1 = *reinterpret_cast<const float4*>(&Bs[k][64 + (tx << 2)]);
      float av[4] = {a.x, a.y, a.z, a.w};
#pragma unroll
      for (int i = 0; i < 4; ++i) {
        acc[i][0] += av[i]*b0.x; acc[i][1] += av[i]*b0.y;
        acc[i][2] += av[i]*b0.z; acc[i][3] += av[i]*b0.w;
        acc[i][4] += av[i]*b1.x; acc[i][5] += av[i]*b1.y;
        acc[i][6] += av[i]*b1.z; acc[i][7] += av[i]*b1.w;
      }
    }
    __syncthreads();
  }
#pragma unroll
  for (int i = 0; i < 4; ++i) {
    int row = m0 + (ty << 2) + i;
    if (row < M) {
      float4 o0 = {acc[i][0], acc[i][1], acc[i][2], acc[i][3]};
      float4 o1 = {acc[i][4], acc[i][5], acc[i][6], acc[i][7]};
      *reinterpret_cast<float4*>(&C[(size_t)row * 128 + (tx << 2)]) = o0;
      *reinterpret_cast<float4*>(&C[(size_t)row * 128 + 64 + (tx << 2)]) = o1;
    }
  }
}

// out[v][c] = bias[c]  (pre-init so scatter accumulates propagate+bias)
__global__ __launch_bounds__(256)
void init_bias(float* __restrict__ out, const float* __restrict__ b) {
  int gid = blockIdx.x * 256 + threadIdx.x;     // over NNODE*32
  int c4 = (gid & 31) << 2;
  float4 v = *reinterpret_cast<const float4*>(&b[c4]);
  *reinterpret_cast<float4*>(&out[(size_t)gid * 4]) = v;
}

// out[dst] += w * X[src], 32 threads per edge (float4 each)
__global__ __launch_bounds__(256)
void scatter_edges(const float* __restrict__ X, float* __restrict__ out,
                   const int* __restrict__ esrc, const int* __restrict__ edst,
                   const float* __restrict__ ew) {
  int gid = blockIdx.x * 256 + threadIdx.x;     // over NEDGE*32
  int e  = gid >> 5;
  int c4 = (gid & 31) << 2;
  int s = esrc[e], d = edst[e];
  float w = ew[e];
  float4 v = *reinterpret_cast<const float4*>(&X[(size_t)s * 128 + c4]);
  float* o = &out[(size_t)d * 128 + c4];
  atomicAdd(o + 0, w * v.x);
  atomicAdd(o + 1, w * v.y);
  atomicAdd(o + 2, w * v.z);
  atomicAdd(o + 3, w * v.w);
}

// gather emb[idx_train] transposed -> embT[128][5000], emb[idx_test] -> qbuf[5000][128],
// onehot[idx_train] -> lab[5000][16]
__global__ __launch_bounds__(256)
void gather_embs(const float* __restrict__ emb, const float* __restrict__ onehot,
                 const int* __restrict__ itr, const int* __restrict__ ite,
                 float* __restrict__ embT, float* __restrict__ qbuf,
                 float* __restrict__ lab) {
  int gid = blockIdx.x * 256 + threadIdx.x;
  if (gid < NTRAIN * NHID) {
    int c = gid / NTRAIN, j = gid - c * NTRAIN;
    embT[gid] = emb[(size_t)itr[j] * NHID + c];
  } else if (gid < 2 * NTRAIN * NHID) {
    int i = gid - NTRAIN * NHID;
    int j = i >> 7, c = i & 127;
    qbuf[i] = emb[(size_t)ite[j] * NHID + c];
  } else if (gid < 2 * NTRAIN * NHID + NTRAIN * NCLS) {
    int i = gid - 2 * NTRAIN * NHID;
    int j = i >> 4, c = i & 15;
    lab[i] = onehot[(size_t)itr[j] * NCLS + c];
  }
}

// Fused: scores (8 test rows/block vs all 5000 train), top-20, softmax, preds.
// Scores live in registers: s[8][20], statically indexed (full unroll).
#define SR 8
__global__ __launch_bounds__(256, 2)
void score_topk(const float* __restrict__ embT,   // [128][5000]
                const float* __restrict__ qbuf,   // [5000][128]
                const float* __restrict__ lab,    // [5000][16]
                float* __restrict__ out) {        // [5000][16]
  __shared__ float q[SR][128];
  __shared__ float rv[4];
  __shared__ int   ri[4];
  __shared__ float tv[TOPK];
  __shared__ int   ti[TOPK];
  const int tid = threadIdx.x;
  const int row0 = blockIdx.x * SR;

  for (int i = tid; i < SR * 128; i += 256) {
    int m = i >> 7, c = i & 127;
    q[m][c] = qbuf[(size_t)(row0 + m) * 128 + c];
  }
  __syncthreads();

  float s[SR][20];
#pragma unroll
  for (int k = 0; k < 20; ++k) {          // k compile-time -> s[][] stays in VGPRs
    int j = k * 256 + tid;
    int jc = j < NTRAIN ? j : NTRAIN - 1;
    const float* bp = embT + jc;
    float acc[SR];
#pragma unroll
    for (int m = 0; m < SR; ++m) acc[m] = 0.f;
    for (int c = 0; c < 128; c += 4) {    // runtime loop (code size)
      float b0 = bp[(size_t)(c + 0) * NTRAIN];
      float b1 = bp[(size_t)(c + 1) * NTRAIN];
      float b2 = bp[(size_t)(c + 2) * NTRAIN];
      float b3 = bp[(size_t)(c + 3) * NTRAIN];
#pragma unroll
      for (int m = 0; m < SR; ++m) {
        float4 qv = *reinterpret_cast<const float4*>(&q[m][c]);
        acc[m] += qv.x * b0 + qv.y * b1 + qv.z * b2 + qv.w * b3;
      }
    }
#pragma unroll
    for (int m = 0; m < SR; ++m) s[m][k] = (j < NTRAIN) ? acc[m] : -INFINITY;
  }

#pragma unroll
  for (int m = 0; m < SR; ++m) {
    for (int it = 0; it < TOPK; ++it) {
      // local argmax over this thread's 20 chunk-slots
      float bv = -INFINITY; int bj = -1;
#pragma unroll
      for (int k = 0; k < 20; ++k) {
        float v = s[m][k];
        if (v > bv) { bv = v; bj = k * 256 + tid; }
      }
      // wave argmax (strict > keeps lowest index on ties, matching top_k)
#pragma unroll
      for (int off = 32; off > 0; off >>= 1) {
        float ov = __shfl_down(bv, off);
        int   oj = __shfl_down(bj, off);
        if (ov > bv) { bv = ov; bj = oj; }
      }
      int wid = tid >> 6;
      if ((tid & 63) == 0) { rv[wid] = bv; ri[wid] = bj; }
      __syncthreads();
      float fv = rv[0]; int fj = ri[0];
#pragma unroll
      for (int w2 = 1; w2 < 4; ++w2) {
        if (rv[w2] > fv) { fv = rv[w2]; fj = ri[w2]; }
      }
      if (tid == 0) { tv[it] = fv; ti[it] = fj; }
      if ((fj & 255) == tid) {            // owner marks its slot consumed
        int rel = fj - tid;
#pragma unroll
        for (int k = 0; k < 20; ++k)
          if (rel == k * 256) s[m][k] = -INFINITY;
      }
      __syncthreads();
    }
    // softmax over the 20 selected + weighted one-hot accumulate
    if (tid < NCLS) {
      float mx = tv[0], sum = 0.f, acc = 0.f;
#pragma unroll
      for (int i = 0; i < TOPK; ++i) {
        float wv = expf(tv[i] - mx);
        sum += wv;
        acc += wv * lab[(size_t)ti[i] * NCLS + tid];
      }
      out[(size_t)(row0 + m) * NCLS + tid] = acc / sum;
    }
    __syncthreads();
  }
}

extern "C" void kernel_launch(void* const* d_in, const int* in_sizes, int n_in,
                              void* d_out, int out_size, void* d_ws, size_t ws_size,
                              hipStream_t stream) {
  const float* feat   = (const float*)d_in[0];
  const float* ew     = (const float*)d_in[1];
  const float* onehot = (const float*)d_in[2];
  const float* W1     = (const float*)d_in[3];
  const float* b1     = (const float*)d_in[4];
  const float* W2     = (const float*)d_in[5];
  const float* b2     = (const float*)d_in[6];
  const int*   ei     = (const int*)d_in[7];
  const int*   itr    = (const int*)d_in[8];
  const int*   ite    = (const int*)d_in[9];
  float* out = (float*)d_out;
  float* ws  = (float*)d_ws;

  float* bufA = ws;                              // [NNODE][128]  X1 then X2
  float* bufH = bufA + (size_t)NNODE * NHID;     // [NNODE][128]  h then emb
  float* embT = bufH + (size_t)NNODE * NHID;     // [128][5000]
  float* qbuf = embT + (size_t)NHID * NTRAIN;    // [5000][128]
  float* lab  = qbuf + (size_t)NTEST * NHID;     // [5000][16]

  const int* esrc = ei;
  const int* edst = ei + NEDGE;

  // layer 1: X1 = feat @ W1 ; h = propagate(X1) + b1  (relu folded into next GEMM)
  gemm128<NFEAT, false><<<(NNODE + 63) / 64, 256, 0, stream>>>(feat, W1, bufA, NNODE);
  init_bias<<<NNODE * 32 / 256, 256, 0, stream>>>(bufH, b1);
  scatter_edges<<<NEDGE * 32 / 256, 256, 0, stream>>>(bufA, bufH, esrc, edst, ew);
  // layer 2: X2 = relu(h) @ W2 ; emb = propagate(X2) + b2
  gemm128<NHID, true><<<(NNODE + 63) / 64, 256, 0, stream>>>(bufH, W2, bufA, NNODE);
  init_bias<<<NNODE * 32 / 256, 256, 0, stream>>>(bufH, b2);
  scatter_edges<<<NEDGE * 32 / 256, 256, 0, stream>>>(bufA, bufH, esrc, edst, ew);
  // gather test/train embeddings (train transposed) + train one-hot labels
  gather_embs<<<(2 * NTRAIN * NHID + NTRAIN * NCLS + 255) / 256, 256, 0, stream>>>(
      bufH, onehot, itr, ite, embT, qbuf, lab);
  // fused score + top-20 + softmax + prediction
  score_topk<<<NTEST / SR, 256, 0, stream>>>(embT, qbuf, lab, out);
}

// Round 2
// 1232.181 us; speedup vs baseline: 2.8930x; 2.8930x over previous
//
#include <hip/hip_runtime.h>
#include <math.h>

#define NNODE 50000
#define NEDGE 800000
#define NFEAT 256
#define NHID  128
#define NTEST 5000
#define NTRAIN 5000
#define NCLS  16
#define TOPK  20

// ---------------- GEMM: C[M x 128] = op(A)[M x KT] @ B[KT x 128] ----------------
template<int KT, bool RELU>
__global__ __launch_bounds__(256)
void gemm128(const float* __restrict__ A, const float* __restrict__ B,
             float* __restrict__ C, int M) {
  __shared__ float As[32][68];   // [k][m], +4 pad
  __shared__ float Bs[32][128];  // [k][n]
  const int tid = threadIdx.x;
  const int ty = tid >> 4, tx = tid & 15;
  const int m0 = blockIdx.x * 64;
  float acc[4][8];
#pragma unroll
  for (int i = 0; i < 4; ++i)
#pragma unroll
    for (int j = 0; j < 8; ++j) acc[i][j] = 0.f;

  for (int k0 = 0; k0 < KT; k0 += 32) {
#pragma unroll
    for (int p = 0; p < 2; ++p) {
      int li = p * 256 + tid;
      int r  = li >> 3;
      int kc = (li & 7) << 2;
      int gr = m0 + r; if (gr > M - 1) gr = M - 1;
      float4 v = *reinterpret_cast<const float4*>(&A[(size_t)gr * KT + k0 + kc]);
      if (RELU) { v.x=fmaxf(v.x,0.f); v.y=fmaxf(v.y,0.f); v.z=fmaxf(v.z,0.f); v.w=fmaxf(v.w,0.f); }
      As[kc+0][r]=v.x; As[kc+1][r]=v.y; As[kc+2][r]=v.z; As[kc+3][r]=v.w;
    }
#pragma unroll
    for (int p = 0; p < 4; ++p) {
      int li = p * 256 + tid;
      int r  = li >> 5;
      int c4 = (li & 31) << 2;
      *reinterpret_cast<float4*>(&Bs[r][c4]) =
        *reinterpret_cast<const float4*>(&B[(size_t)(k0 + r) * 128 + c4]);
    }
    __syncthreads();
#pragma unroll
    for (int k = 0; k < 32; ++k) {
      float4 a  = *reinterpret_cast<const float4*>(&As[k][ty << 2]);
      float4 b0 = *reinterpret_cast<const float4*>(&Bs[k][tx << 2]);
      float4 b1 = *reinterpret_cast<const float4*>(&Bs[k][64 + (tx << 2)]);
      float av[4] = {a.x, a.y, a.z, a.w};
#pragma unroll
      for (int i = 0; i < 4; ++i) {
        acc[i][0] += av[i]*b0.x; acc[i][1] += av[i]*b0.y;
        acc[i][2] += av[i]*b0.z; acc[i][3] += av[i]*b0.w;
        acc[i][4] += av[i]*b1.x; acc[i][5] += av[i]*b1.y;
        acc[i][6] += av[i]*b1.z; acc[i][7] += av[i]*b1.w;
      }
    }
    __syncthreads();
  }
#pragma unroll
  for (int i = 0; i < 4; ++i) {
    int row = m0 + (ty << 2) + i;
    if (row < M) {
      float4 o0 = {acc[i][0], acc[i][1], acc[i][2], acc[i][3]};
      float4 o1 = {acc[i][4], acc[i][5], acc[i][6], acc[i][7]};
      *reinterpret_cast<float4*>(&C[(size_t)row * 128 + (tx << 2)]) = o0;
      *reinterpret_cast<float4*>(&C[(size_t)row * 128 + 64 + (tx << 2)]) = o1;
    }
  }
}

// ---------------- CSR build (per call, deterministic work) ----------------
__global__ __launch_bounds__(256)
void zero_cnt(int* __restrict__ cnt) {
  int i = blockIdx.x * 256 + threadIdx.x;
  if (i < NNODE) cnt[i] = 0;
}

__global__ __launch_bounds__(256)
void hist_dst(const int* __restrict__ edst, int* __restrict__ cnt) {
  int e = blockIdx.x * 256 + threadIdx.x;
  if (e < NEDGE) atomicAdd(&cnt[edst[e]], 1);
}

// single-block in-place exclusive scan of cnt[NNODE]
#define SCHUNK 196
__global__ __launch_bounds__(256)
void scan_cnt(int* __restrict__ cnt) {
  __shared__ int part[256];
  const int t = threadIdx.x;
  const int base = t * SCHUNK;
  int s = 0;
  for (int i = 0; i < SCHUNK; ++i) {
    int idx = base + i;
    if (idx < NNODE) s += cnt[idx];
  }
  part[t] = s;
  __syncthreads();
  for (int off = 1; off < 256; off <<= 1) {
    int v = (t >= off) ? part[t - off] : 0;
    __syncthreads();
    part[t] += v;
    __syncthreads();
  }
  int run = part[t] - s;           // exclusive offset of this chunk
  for (int i = 0; i < SCHUNK; ++i) {
    int idx = base + i;
    if (idx < NNODE) { int c = cnt[idx]; cnt[idx] = run; run += c; }
  }
}

// scatter edges into CSR slots; cursor starts as exclusive offsets,
// ends as segment END offsets (cursor[d] == off[d+1])
__global__ __launch_bounds__(256)
void fill_csr(const int* __restrict__ esrc, const int* __restrict__ edst,
              const float* __restrict__ ew, int* __restrict__ cursor,
              int2* __restrict__ packed) {
  int e = blockIdx.x * 256 + threadIdx.x;
  if (e < NEDGE) {
    int d = edst[e];
    int p = atomicAdd(&cursor[d], 1);
    packed[p] = make_int2(esrc[e], __float_as_int(ew[e]));
  }
}

// ---------------- propagate as gather: out[d][c] = b[c] + sum_e w*X[src][c] ----
__global__ __launch_bounds__(256)
void gather_nodes(const float* __restrict__ X, float* __restrict__ out,
                  const int* __restrict__ endoff, const int2* __restrict__ packed,
                  const float* __restrict__ bias) {
  int node = blockIdx.x * 2 + (threadIdx.x >> 7);
  int c = threadIdx.x & 127;
  int beg = node ? endoff[node - 1] : 0;
  int end = endoff[node];
  float acc = bias[c], acc2 = 0.f;
  int e = beg;
  for (; e + 1 < end; e += 2) {
    int2 p0 = packed[e], p1 = packed[e + 1];
    acc  += __int_as_float(p0.y) * X[(size_t)p0.x * 128 + c];
    acc2 += __int_as_float(p1.y) * X[(size_t)p1.x * 128 + c];
  }
  if (e < end) {
    int2 p = packed[e];
    acc += __int_as_float(p.y) * X[(size_t)p.x * 128 + c];
  }
  out[(size_t)node * 128 + c] = acc + acc2;
}

// ---------------- gathers for scoring ----------------
__global__ __launch_bounds__(256)
void gather_embs(const float* __restrict__ emb, const float* __restrict__ onehot,
                 const int* __restrict__ itr, const int* __restrict__ ite,
                 float* __restrict__ embT, float* __restrict__ qbuf,
                 float* __restrict__ lab) {
  int gid = blockIdx.x * 256 + threadIdx.x;
  if (gid < NTRAIN * NHID) {
    int c = gid / NTRAIN, j = gid - c * NTRAIN;
    embT[gid] = emb[(size_t)itr[j] * NHID + c];
  } else if (gid < 2 * NTRAIN * NHID) {
    int i = gid - NTRAIN * NHID;
    int j = i >> 7, c = i & 127;
    qbuf[i] = emb[(size_t)ite[j] * NHID + c];
  } else if (gid < 2 * NTRAIN * NHID + NTRAIN * NCLS) {
    int i = gid - 2 * NTRAIN * NHID;
    int j = i >> 4, c = i & 15;
    lab[i] = onehot[(size_t)itr[j] * NCLS + c];
  }
}

// ---------------- fused score + top-20 + softmax + preds ----------------
#define SR 8
__global__ __launch_bounds__(256, 2)
void score_topk(const float* __restrict__ embT,   // [128][5000]
                const float* __restrict__ qbuf,   // [5000][128]
                const float* __restrict__ lab,    // [5000][16]
                float* __restrict__ out) {        // [5000][16]
  __shared__ float q[SR][128];
  __shared__ float rv[4];
  __shared__ int   ri[4];
  __shared__ float tv[TOPK];
  __shared__ int   ti[TOPK];
  const int tid = threadIdx.x;
  const int row0 = blockIdx.x * SR;

  for (int i = tid; i < SR * 128; i += 256) {
    int m = i >> 7, c = i & 127;
    q[m][c] = qbuf[(size_t)(row0 + m) * 128 + c];
  }
  __syncthreads();

  float s[SR][20];
#pragma unroll
  for (int k = 0; k < 20; ++k) {
    int j = k * 256 + tid;
    int jc = j < NTRAIN ? j : NTRAIN - 1;
    const float* bp = embT + jc;
    float acc[SR];
#pragma unroll
    for (int m = 0; m < SR; ++m) acc[m] = 0.f;
    for (int c = 0; c < 128; c += 4) {
      float b0 = bp[(size_t)(c + 0) * NTRAIN];
      float b1 = bp[(size_t)(c + 1) * NTRAIN];
      float b2 = bp[(size_t)(c + 2) * NTRAIN];
      float b3 = bp[(size_t)(c + 3) * NTRAIN];
#pragma unroll
      for (int m = 0; m < SR; ++m) {
        float4 qv = *reinterpret_cast<const float4*>(&q[m][c]);
        acc[m] += qv.x * b0 + qv.y * b1 + qv.z * b2 + qv.w * b3;
      }
    }
#pragma unroll
    for (int m = 0; m < SR; ++m) s[m][k] = (j < NTRAIN) ? acc[m] : -INFINITY;
  }

#pragma unroll
  for (int m = 0; m < SR; ++m) {
    for (int it = 0; it < TOPK; ++it) {
      float bv = -INFINITY; int bj = -1;
#pragma unroll
      for (int k = 0; k < 20; ++k) {
        float v = s[m][k];
        if (v > bv) { bv = v; bj = k * 256 + tid; }
      }
#pragma unroll
      for (int off = 32; off > 0; off >>= 1) {
        float ov = __shfl_down(bv, off);
        int   oj = __shfl_down(bj, off);
        if (ov > bv) { bv = ov; bj = oj; }
      }
      int wid = tid >> 6;
      if ((tid & 63) == 0) { rv[wid] = bv; ri[wid] = bj; }
      __syncthreads();
      float fv = rv[0]; int fj = ri[0];
#pragma unroll
      for (int w2 = 1; w2 < 4; ++w2) {
        if (rv[w2] > fv) { fv = rv[w2]; fj = ri[w2]; }
      }
      if (tid == 0) { tv[it] = fv; ti[it] = fj; }
      if ((fj & 255) == tid) {
        int rel = fj - tid;
#pragma unroll
        for (int k = 0; k < 20; ++k)
          if (rel == k * 256) s[m][k] = -INFINITY;
      }
      __syncthreads();
    }
    if (tid < NCLS) {
      float mx = tv[0], sum = 0.f, acc = 0.f;
#pragma unroll
      for (int i = 0; i < TOPK; ++i) {
        float wv = expf(tv[i] - mx);
        sum += wv;
        acc += wv * lab[(size_t)ti[i] * NCLS + tid];
      }
      out[(size_t)(row0 + m) * NCLS + tid] = acc / sum;
    }
    __syncthreads();
  }
}

extern "C" void kernel_launch(void* const* d_in, const int* in_sizes, int n_in,
                              void* d_out, int out_size, void* d_ws, size_t ws_size,
                              hipStream_t stream) {
  const float* feat   = (const float*)d_in[0];
  const float* ew     = (const float*)d_in[1];
  const float* onehot = (const float*)d_in[2];
  const float* W1     = (const float*)d_in[3];
  const float* b1     = (const float*)d_in[4];
  const float* W2     = (const float*)d_in[5];
  const float* b2     = (const float*)d_in[6];
  const int*   ei     = (const int*)d_in[7];
  const int*   itr    = (const int*)d_in[8];
  const int*   ite    = (const int*)d_in[9];
  float* out = (float*)d_out;
  float* ws  = (float*)d_ws;

  // workspace layout (CSR region aliased by embT/qbuf/lab after propagates)
  float* bufA   = ws;                                  // [NNODE][128]
  float* bufH   = bufA + (size_t)NNODE * NHID;         // [NNODE][128]
  int*   cursor = (int*)(bufH + (size_t)NNODE * NHID); // [NNODE] (+pad to 16)
  int2*  packed = (int2*)(cursor + ((NNODE + 15) & ~15)); // [NEDGE]
  float* embT   = (float*)packed;                      // [128][5000]   (aliases packed)
  float* qbuf   = embT + (size_t)NHID * NTRAIN;        // [5000][128]
  float* lab    = qbuf + (size_t)NTEST * NHID;         // [5000][16]

  const int* esrc = ei;
  const int* edst = ei + NEDGE;

  // ---- CSR build ----
  zero_cnt<<<(NNODE + 255) / 256, 256, 0, stream>>>(cursor);
  hist_dst<<<(NEDGE + 255) / 256, 256, 0, stream>>>(edst, cursor);
  scan_cnt<<<1, 256, 0, stream>>>(cursor);
  fill_csr<<<(NEDGE + 255) / 256, 256, 0, stream>>>(esrc, edst, ew, cursor, packed);
  // after fill: cursor[d] == end offset of segment d

  // ---- layer 1: X1 = feat @ W1 ; h = gather(X1) + b1 ----
  gemm128<NFEAT, false><<<(NNODE + 63) / 64, 256, 0, stream>>>(feat, W1, bufA, NNODE);
  gather_nodes<<<NNODE / 2, 256, 0, stream>>>(bufA, bufH, cursor, packed, b1);
  // ---- layer 2: X2 = relu(h) @ W2 ; emb = gather(X2) + b2 ----
  gemm128<NHID, true><<<(NNODE + 63) / 64, 256, 0, stream>>>(bufH, W2, bufA, NNODE);
  gather_nodes<<<NNODE / 2, 256, 0, stream>>>(bufA, bufH, cursor, packed, b2);

  // ---- scoring (embT/qbuf/lab alias the now-dead CSR packed region) ----
  gather_embs<<<(2 * NTRAIN * NHID + NTRAIN * NCLS + 255) / 256, 256, 0, stream>>>(
      bufH, onehot, itr, ite, embT, qbuf, lab);
  score_topk<<<NTEST / SR, 256, 0, stream>>>(embT, qbuf, lab, out);
}

// Round 3
// 743.165 us; speedup vs baseline: 4.7967x; 1.6580x over previous
//
#include <hip/hip_runtime.h>
#include <math.h>

#define NNODE 50000
#define NEDGE 800000
#define NFEAT 256
#define NHID  128
#define NTEST 5000
#define NTRAIN 5000
#define NCLS  16
#define TOPK  20
#define JT    1024          // j-tile for scoring
#define NJT   5             // ceil(5000/1024)

// ---------------- GEMM: C[M x 128] = op(A)[M x KT] @ B[KT x 128] ----------------
template<int KT, bool RELU>
__global__ __launch_bounds__(256)
void gemm128(const float* __restrict__ A, const float* __restrict__ B,
             float* __restrict__ C, int M) {
  __shared__ float As[32][68];   // [k][m], +4 pad
  __shared__ float Bs[32][128];  // [k][n]
  const int tid = threadIdx.x;
  const int ty = tid >> 4, tx = tid & 15;
  const int m0 = blockIdx.x * 64;
  float acc[4][8];
#pragma unroll
  for (int i = 0; i < 4; ++i)
#pragma unroll
    for (int j = 0; j < 8; ++j) acc[i][j] = 0.f;

  for (int k0 = 0; k0 < KT; k0 += 32) {
#pragma unroll
    for (int p = 0; p < 2; ++p) {
      int li = p * 256 + tid;
      int r  = li >> 3;
      int kc = (li & 7) << 2;
      int gr = m0 + r; if (gr > M - 1) gr = M - 1;
      float4 v = *reinterpret_cast<const float4*>(&A[(size_t)gr * KT + k0 + kc]);
      if (RELU) { v.x=fmaxf(v.x,0.f); v.y=fmaxf(v.y,0.f); v.z=fmaxf(v.z,0.f); v.w=fmaxf(v.w,0.f); }
      As[kc+0][r]=v.x; As[kc+1][r]=v.y; As[kc+2][r]=v.z; As[kc+3][r]=v.w;
    }
#pragma unroll
    for (int p = 0; p < 4; ++p) {
      int li = p * 256 + tid;
      int r  = li >> 5;
      int c4 = (li & 31) << 2;
      *reinterpret_cast<float4*>(&Bs[r][c4]) =
        *reinterpret_cast<const float4*>(&B[(size_t)(k0 + r) * 128 + c4]);
    }
    __syncthreads();
#pragma unroll
    for (int k = 0; k < 32; ++k) {
      float4 a  = *reinterpret_cast<const float4*>(&As[k][ty << 2]);
      float4 b0 = *reinterpret_cast<const float4*>(&Bs[k][tx << 2]);
      float4 b1 = *reinterpret_cast<const float4*>(&Bs[k][64 + (tx << 2)]);
      float av[4] = {a.x, a.y, a.z, a.w};
#pragma unroll
      for (int i = 0; i < 4; ++i) {
        acc[i][0] += av[i]*b0.x; acc[i][1] += av[i]*b0.y;
        acc[i][2] += av[i]*b0.z; acc[i][3] += av[i]*b0.w;
        acc[i][4] += av[i]*b1.x; acc[i][5] += av[i]*b1.y;
        acc[i][6] += av[i]*b1.z; acc[i][7] += av[i]*b1.w;
      }
    }
    __syncthreads();
  }
#pragma unroll
  for (int i = 0; i < 4; ++i) {
    int row = m0 + (ty << 2) + i;
    if (row < M) {
      float4 o0 = {acc[i][0], acc[i][1], acc[i][2], acc[i][3]};
      float4 o1 = {acc[i][4], acc[i][5], acc[i][6], acc[i][7]};
      *reinterpret_cast<float4*>(&C[(size_t)row * 128 + (tx << 2)]) = o0;
      *reinterpret_cast<float4*>(&C[(size_t)row * 128 + 64 + (tx << 2)]) = o1;
    }
  }
}

// ---------------- CSR build ----------------
__global__ __launch_bounds__(256)
void zero_cnt(int* __restrict__ cnt) {
  int i = blockIdx.x * 256 + threadIdx.x;
  if (i < NNODE) cnt[i] = 0;
}

__global__ __launch_bounds__(256)
void hist_dst(const int* __restrict__ edst, int* __restrict__ cnt) {
  int e = blockIdx.x * 256 + threadIdx.x;
  if (e < NEDGE) atomicAdd(&cnt[edst[e]], 1);
}

#define SCHUNK 196
__global__ __launch_bounds__(256)
void scan_cnt(int* __restrict__ cnt) {
  __shared__ int part[256];
  const int t = threadIdx.x;
  const int base = t * SCHUNK;
  int s = 0;
  for (int i = 0; i < SCHUNK; ++i) {
    int idx = base + i;
    if (idx < NNODE) s += cnt[idx];
  }
  part[t] = s;
  __syncthreads();
  for (int off = 1; off < 256; off <<= 1) {
    int v = (t >= off) ? part[t - off] : 0;
    __syncthreads();
    part[t] += v;
    __syncthreads();
  }
  int run = part[t] - s;
  for (int i = 0; i < SCHUNK; ++i) {
    int idx = base + i;
    if (idx < NNODE) { int c = cnt[idx]; cnt[idx] = run; run += c; }
  }
}

__global__ __launch_bounds__(256)
void fill_csr(const int* __restrict__ esrc, const int* __restrict__ edst,
              const float* __restrict__ ew, int* __restrict__ cursor,
              int2* __restrict__ packed) {
  int e = blockIdx.x * 256 + threadIdx.x;
  if (e < NEDGE) {
    int d = edst[e];
    int p = atomicAdd(&cursor[d], 1);
    packed[p] = make_int2(esrc[e], __float_as_int(ew[e]));
  }
}

// ---------------- propagate as gather ----------------
__global__ __launch_bounds__(256)
void gather_nodes(const float* __restrict__ X, float* __restrict__ out,
                  const int* __restrict__ endoff, const int2* __restrict__ packed,
                  const float* __restrict__ bias) {
  int node = blockIdx.x * 2 + (threadIdx.x >> 7);
  int c = threadIdx.x & 127;
  int beg = node ? endoff[node - 1] : 0;
  int end = endoff[node];
  float acc = bias[c], acc2 = 0.f;
  int e = beg;
  for (; e + 1 < end; e += 2) {
    int2 p0 = packed[e], p1 = packed[e + 1];
    acc  += __int_as_float(p0.y) * X[(size_t)p0.x * 128 + c];
    acc2 += __int_as_float(p1.y) * X[(size_t)p1.x * 128 + c];
  }
  if (e < end) {
    int2 p = packed[e];
    acc += __int_as_float(p.y) * X[(size_t)p.x * 128 + c];
  }
  out[(size_t)node * 128 + c] = acc + acc2;
}

// ---------------- gathers for scoring ----------------
__global__ __launch_bounds__(256)
void gather_embs(const float* __restrict__ emb, const float* __restrict__ onehot,
                 const int* __restrict__ itr, const int* __restrict__ ite,
                 float* __restrict__ embT, float* __restrict__ qbuf,
                 float* __restrict__ lab) {
  int gid = blockIdx.x * 256 + threadIdx.x;
  if (gid < NTRAIN * NHID) {
    int c = gid / NTRAIN, j = gid - c * NTRAIN;
    embT[gid] = emb[(size_t)itr[j] * NHID + c];
  } else if (gid < 2 * NTRAIN * NHID) {
    int i = gid - NTRAIN * NHID;
    int j = i >> 7, c = i & 127;
    qbuf[i] = emb[(size_t)ite[j] * NHID + c];
  } else if (gid < 2 * NTRAIN * NHID + NTRAIN * NCLS) {
    int i = gid - 2 * NTRAIN * NHID;
    int j = i >> 4, c = i & 15;
    lab[i] = onehot[(size_t)itr[j] * NCLS + c];
  }
}

// ---------------- score tile + per-tile top-20 ----------------
// grid (625, NJT): 8 test rows x 1024 train cols per block.
// Compute: acc[8][4] regs (static). Scores -> LDS. Selection: wave w owns
// rows 2w,2w+1; 16 vals/lane in static regs; 20x shuffle-butterfly argmax.
__global__ __launch_bounds__(256)
void score_tile(const float* __restrict__ embT,   // [128][5000]
                const float* __restrict__ qbuf,   // [5000][128]
                float* __restrict__ cand_v,       // [5000][NJT][20]
                int*   __restrict__ cand_i) {
  __shared__ float q[8][128];
  __shared__ float s[8][JT];
  const int tid = threadIdx.x;
  const int row0 = blockIdx.x * 8;
  const int j0 = blockIdx.y * JT;

  for (int i = tid; i < 8 * 128; i += 256)
    q[i >> 7][i & 127] = qbuf[(size_t)(row0 + (i >> 7)) * 128 + (i & 127)];
  __syncthreads();

  // base pointers per j-slot (clamped for OOB tail of last tile)
  const float* bp[4];
  int jg[4];
#pragma unroll
  for (int t = 0; t < 4; ++t) {
    jg[t] = j0 + tid + 256 * t;
    int jc = jg[t] < NTRAIN ? jg[t] : NTRAIN - 1;
    bp[t] = embT + jc;
  }
  float acc[8][4];
#pragma unroll
  for (int m = 0; m < 8; ++m)
#pragma unroll
    for (int t = 0; t < 4; ++t) acc[m][t] = 0.f;

#pragma unroll 4
  for (int c = 0; c < 128; c += 4) {
    float b[4][4];
#pragma unroll
    for (int u = 0; u < 4; ++u)
#pragma unroll
      for (int t = 0; t < 4; ++t)
        b[u][t] = bp[t][(size_t)(c + u) * NTRAIN];
#pragma unroll
    for (int m = 0; m < 8; ++m) {
      float4 qv = *reinterpret_cast<const float4*>(&q[m][c]);
#pragma unroll
      for (int t = 0; t < 4; ++t)
        acc[m][t] += qv.x * b[0][t] + qv.y * b[1][t] + qv.z * b[2][t] + qv.w * b[3][t];
    }
  }

#pragma unroll
  for (int m = 0; m < 8; ++m)
#pragma unroll
    for (int t = 0; t < 4; ++t)
      s[m][tid + 256 * t] = (jg[t] < NTRAIN) ? acc[m][t] : -INFINITY;
  __syncthreads();

  // per-wave selection, 2 rows per wave, no block barriers
  const int wv = tid >> 6, lane = tid & 63;
#pragma unroll
  for (int r = 0; r < 2; ++r) {
    const int m = wv * 2 + r;
    float v[16];
#pragma unroll
    for (int k = 0; k < 16; ++k) v[k] = s[m][lane + 64 * k];   // stride-1: conflict-free
    float selv = 0.f; int seli = 0;
#pragma unroll
    for (int it = 0; it < TOPK; ++it) {
      float bv = v[0]; int bk = 0;
#pragma unroll
      for (int k = 1; k < 16; ++k)
        if (v[k] > bv) { bv = v[k]; bk = k; }
      int bj = lane + 64 * bk;
      // butterfly argmax, tie -> lowest index
#pragma unroll
      for (int off = 1; off < 64; off <<= 1) {
        float ov = __shfl_xor(bv, off);
        int   oj = __shfl_xor(bj, off);
        if (ov > bv || (ov == bv && oj < bj)) { bv = ov; bj = oj; }
      }
      if (lane == it) { selv = bv; seli = j0 + bj; }
      int ck = bj >> 6;
      if ((bj & 63) == lane) {
#pragma unroll
        for (int k = 0; k < 16; ++k)
          if (k == ck) v[k] = -INFINITY;
      }
    }
    if (lane < TOPK) {
      size_t o = ((size_t)(row0 + m) * NJT + blockIdx.y) * TOPK + lane;
      cand_v[o] = selv;
      cand_i[o] = seli;
    }
  }
}

// ---------------- merge candidates + softmax + preds ----------------
// 1 wave per row; 100 candidates -> top-20 -> softmax -> 16-class output.
__global__ __launch_bounds__(256)
void merge_topk(const float* __restrict__ cand_v, const int* __restrict__ cand_i,
                const float* __restrict__ lab, float* __restrict__ out) {
  const int tid = threadIdx.x;
  const int wv = tid >> 6, lane = tid & 63;
  const int row = blockIdx.x * 4 + wv;
  const size_t base = (size_t)row * (NJT * TOPK);

  float c0 = -INFINITY, c1 = -INFINITY;
  int i0 = 0x7fffffff, i1 = 0x7fffffff;
  if (lane < NJT * TOPK)      { c0 = cand_v[base + lane];      i0 = cand_i[base + lane]; }
  if (lane + 64 < NJT * TOPK) { c1 = cand_v[base + lane + 64]; i1 = cand_i[base + lane + 64]; }

  float selv = 0.f; int seli = 0;
#pragma unroll
  for (int it = 0; it < TOPK; ++it) {
    float bv = c0; int bj = i0;
    if (c1 > bv || (c1 == bv && i1 < bj)) { bv = c1; bj = i1; }
#pragma unroll
    for (int off = 1; off < 64; off <<= 1) {
      float ov = __shfl_xor(bv, off);
      int   oj = __shfl_xor(bj, off);
      if (ov > bv || (ov == bv && oj < bj)) { bv = ov; bj = oj; }
    }
    if (lane == it) { selv = bv; seli = bj; }
    if (i0 == bj) c0 = -INFINITY;   // candidate indices are unique per row
    if (i1 == bj) c1 = -INFINITY;
  }
  // softmax over the 20 (lane 0 holds the max — selected in descending order)
  float mx = __shfl(selv, 0);
  float w = (lane < TOPK) ? expf(selv - mx) : 0.f;
  float sum = w;
#pragma unroll
  for (int off = 1; off < 64; off <<= 1) sum += __shfl_xor(sum, off);

  float acc = 0.f;
#pragma unroll
  for (int i = 0; i < TOPK; ++i) {
    float wi = __shfl(w, i);
    int   ji = __shfl(seli, i);
    if (lane < NCLS) acc += wi * lab[(size_t)ji * NCLS + lane];
  }
  if (lane < NCLS) out[(size_t)row * NCLS + lane] = acc / sum;
}

extern "C" void kernel_launch(void* const* d_in, const int* in_sizes, int n_in,
                              void* d_out, int out_size, void* d_ws, size_t ws_size,
                              hipStream_t stream) {
  const float* feat   = (const float*)d_in[0];
  const float* ew     = (const float*)d_in[1];
  const float* onehot = (const float*)d_in[2];
  const float* W1     = (const float*)d_in[3];
  const float* b1     = (const float*)d_in[4];
  const float* W2     = (const float*)d_in[5];
  const float* b2     = (const float*)d_in[6];
  const int*   ei     = (const int*)d_in[7];
  const int*   itr    = (const int*)d_in[8];
  const int*   ite    = (const int*)d_in[9];
  float* out = (float*)d_out;
  float* ws  = (float*)d_ws;

  float* bufA   = ws;                                  // [NNODE][128]
  float* bufH   = bufA + (size_t)NNODE * NHID;         // [NNODE][128]
  int*   cursor = (int*)(bufH + (size_t)NNODE * NHID); // [NNODE]
  int2*  packed = (int2*)(cursor + ((NNODE + 15) & ~15)); // [NEDGE]
  float* embT   = (float*)packed;                      // [128][5000] (aliases dead packed)
  float* qbuf   = embT + (size_t)NHID * NTRAIN;        // [5000][128]
  float* lab    = qbuf + (size_t)NTEST * NHID;         // [5000][16]
  float* cand_v = bufA;                                // [5000][NJT][20] (bufA dead by then)
  int*   cand_i = (int*)(bufA + (size_t)NTEST * NJT * TOPK);

  const int* esrc = ei;
  const int* edst = ei + NEDGE;

  // CSR build
  zero_cnt<<<(NNODE + 255) / 256, 256, 0, stream>>>(cursor);
  hist_dst<<<(NEDGE + 255) / 256, 256, 0, stream>>>(edst, cursor);
  scan_cnt<<<1, 256, 0, stream>>>(cursor);
  fill_csr<<<(NEDGE + 255) / 256, 256, 0, stream>>>(esrc, edst, ew, cursor, packed);

  // layer 1 + layer 2
  gemm128<NFEAT, false><<<(NNODE + 63) / 64, 256, 0, stream>>>(feat, W1, bufA, NNODE);
  gather_nodes<<<NNODE / 2, 256, 0, stream>>>(bufA, bufH, cursor, packed, b1);
  gemm128<NHID, true><<<(NNODE + 63) / 64, 256, 0, stream>>>(bufH, W2, bufA, NNODE);
  gather_nodes<<<NNODE / 2, 256, 0, stream>>>(bufA, bufH, cursor, packed, b2);

  // scoring
  gather_embs<<<(2 * NTRAIN * NHID + NTRAIN * NCLS + 255) / 256, 256, 0, stream>>>(
      bufH, onehot, itr, ite, embT, qbuf, lab);
  score_tile<<<dim3(NTEST / 8, NJT), 256, 0, stream>>>(embT, qbuf, cand_v, cand_i);
  merge_topk<<<NTEST / 4, 256, 0, stream>>>(cand_v, cand_i, lab, out);
}